// Round 1
// 8388.471 us; speedup vs baseline: 1.0348x; 1.0348x over previous
//
#include <hip/hip_runtime.h>

// Bidirectional LSTM L=512, B=64, E=H=512 fp32 — MFMA split-bf16 persistent kernel.
// Round 4: (1) x-projection inputs removed from the critical path: x(t) is
// gathered/split ONCE (distributed 1/128 per block) and pushed through the L3
// exchange ring XW=4 steps ahead of use — the existing h-flag chain already
// orders it (x(s+4) publish precedes flag(s+1); consumer of x(s) waits flag>=s).
// (2) Both x and h MFMA B-fragments are loaded DIRECTLY from L3 into registers
// (packed hi|lo u32 -> 2x v_perm_b32 per u64): the whole zhi/zlo LDS staging
// (133KB, 2 barriers/step, 1.35e8 bank conflicts) is gone. (3) Per-wave flag
// polling (__all over 2 slots/lane) replaces barrier-paced __syncthreads_and.
// (4) k split 4-ways x 2 col-halves per wave: A-frags drop 128->64 VGPRs so
// in-flight x(64)+h(32) load registers fit 8 waves/CU.

#define LL 512
#define BB 64
#define HH 512
#define NBLK 256
#define NTHR 512
#define XW 4   // x pipeline depth (steps ahead)
#define XR 8   // x ring slots (power of 2 > XW)

typedef __attribute__((ext_vector_type(8))) __bf16 bf16x8;
typedef __attribute__((ext_vector_type(4))) float f32x4;
typedef unsigned int u32;
typedef unsigned long long u64;
typedef unsigned short u16;

struct Params {
  const int* tokens; const float* mask; const float* emb;
  const float* WihF; const float* WhhF; const float* bihF; const float* bhhF;
  const float* WihB; const float* WhhB; const float* bihB; const float* bhhB;
  float* out; u32* hx; int* bar;
};

__device__ __forceinline__ float sigf(float x)  { return 1.0f / (1.0f + __expf(-x)); }
__device__ __forceinline__ float tanh2(float x) { return 2.0f / (1.0f + __expf(-2.0f * x)) - 1.0f; }

__device__ __forceinline__ void split1(float v, u16& hi, u16& lo) {
  __bf16 h = (__bf16)v;
  __bf16 l = (__bf16)(v - (float)h);
  hi = __builtin_bit_cast(u16, h);
  lo = __builtin_bit_cast(u16, l);
}

// 4x u64 of packed (hi|lo<<16) elements -> bf16x8 hi-plane + bf16x8 lo-plane
__device__ __forceinline__ void unpack4(const u64* q, bf16x8& bh, bf16x8& bl) {
  union U { u32 w[4]; bf16x8 v; } H, L;
  #pragma unroll
  for (int i = 0; i < 4; ++i) {
    u32 lo = (u32)q[i], hi = (u32)(q[i] >> 32);
    H.w[i] = __builtin_amdgcn_perm(hi, lo, 0x05040100u);  // low16s  (bf16 hi bits)
    L.w[i] = __builtin_amdgcn_perm(hi, lo, 0x07060302u);  // high16s (bf16 lo bits)
  }
  bh = H.v; bl = L.v;
}

#define MF(A, B, C) C = __builtin_amdgcn_mfma_f32_16x16x32_bf16(A, B, C, 0, 0, 0)
#define LDA(P)    __hip_atomic_load((P), __ATOMIC_RELAXED, __HIP_MEMORY_SCOPE_AGENT)
#define STA(P, V) __hip_atomic_store((P), (V), __ATOMIC_RELAXED, __HIP_MEMORY_SCOPE_AGENT)

__launch_bounds__(NTHR, 1)
__global__ void lstm_mfma(Params p) {
  __shared__ f32x4 red[16][64];   // [wv*2+tile][lane] k-quarter partials (16 KB)

  const int tid  = threadIdx.x;
  const int blk  = blockIdx.x;
  const int dir  = blk >> 7;          // 0=fwd 1=bwd
  const int q    = blk & 127;
  const int j0   = q << 2;            // 4 owned h-units
  const int lane = tid & 63;
  const int wv   = tid >> 6;          // 8 waves
  const int kq   = wv >> 1;           // k-quarter (128 k each)
  const int nh   = wv & 1;            // col-half (32 batch cols)
  const int quad = lane >> 4;
  const int mrow = lane & 15;
  const int cb0  = (nh * 32 + mrow) << 9;   // u32 index base, col-tile 0
  const int cb1  = cb0 + (16 << 9);         // col-tile 1
  const int kko  = kq * 128 + quad * 8;

  const float* __restrict__ Wih = dir ? p.WihB : p.WihF;
  const float* __restrict__ Whh = dir ? p.WhhB : p.WhhF;
  const float* bih = dir ? p.bihB : p.bihF;
  const float* bhh = dir ? p.bhhB : p.bhhF;

  // ---- one-time: weights -> register A-fragments, split bf16 hi/lo ----
  // A row m -> gate g=m&3, unit jj=m>>2 => C regs 0..3 = 4 gates of unit quad.
  bf16x8 aXhi[4], aXlo[4], aHhi[4], aHlo[4];
  const int grow = (mrow & 3) * HH + j0 + (mrow >> 2);
  #pragma unroll
  for (int s4 = 0; s4 < 4; ++s4) {
    const int kb = kko + s4 * 32;
    const float* wp = Wih + (size_t)grow * HH + kb;
    const float* wq = Whh + (size_t)grow * HH + kb;
    #pragma unroll
    for (int j = 0; j < 8; ++j) {
      float v = wp[j];
      __bf16 h = (__bf16)v;
      aXhi[s4][j] = h; aXlo[s4][j] = (__bf16)(v - (float)h);
      float u = wq[j];
      __bf16 g = (__bf16)u;
      aHhi[s4][j] = g; aHlo[s4][j] = (__bf16)(u - (float)g);
    }
  }
  float bias4[4];
  #pragma unroll
  for (int g = 0; g < 4; ++g)
    bias4[g] = bih[g * HH + j0 + quad] + bhh[g * HH + j0 + quad];

  u32* hx    = p.hx;                       // [dir][buf][b][k] packed hi|lo<<16
  u32* xr    = p.hx + 2 * 2 * HH * BB;     // x ring [dir][slot][b][k], same packing
  int* slots = p.bar;                      // h-step flags [dir][128]
  int* pslot = p.bar + 256;                // prologue handshake [dir][128]
  const int gb = dir * 128;

  // x producer role: waves 4..7, lanes 0..15 => 64 producers of float4 each.
  // Block q covers b = q>>1, k-range (q&1)*256..+255.
  const bool isprod = (wv >= 4) && (lane < 16);
  const int pid = (wv - 4) * 16 + lane;
  const int pb  = q >> 1;
  const int pk  = ((q & 1) << 8) + pid * 4;

  // ---- prologue: publish x(0..XW-1), grid handshake ----
  if (isprod) {
    #pragma unroll
    for (int w = 0; w < XW; ++w) {
      const int tp = dir ? (LL - 1 - w) : w;
      const int tok = p.tokens[tp * BB + pb];
      float4 v = make_float4(0.f, 0.f, 0.f, 0.f);
      if (tok >= 0) v = *(const float4*)(p.emb + (size_t)tok * HH + pk);
      u16 h0,h1,h2,h3,l0,l1,l2,l3;
      split1(v.x,h0,l0); split1(v.y,h1,l1); split1(v.z,h2,l2); split1(v.w,h3,l3);
      u64 w0 = ((u64)((u32)h0 | ((u32)l0 << 16))) | (((u64)((u32)h1 | ((u32)l1 << 16))) << 32);
      u64 w1 = ((u64)((u32)h2 | ((u32)l2 << 16))) | (((u64)((u32)h3 | ((u32)l3 << 16))) << 32);
      u64* dst = (u64*)(xr + ((size_t)(dir * XR + w)) * (HH * BB)) + (((pb << 9) + pk) >> 1);
      STA(&dst[0], w0); STA(&dst[1], w1);
    }
  }
  asm volatile("s_waitcnt vmcnt(0)" ::: "memory");
  __syncthreads();
  if (tid == 0) STA(&pslot[gb + q], 1);
  for (;;) {
    int a = LDA(&pslot[gb + lane * 2]);
    int b = LDA(&pslot[gb + lane * 2 + 1]);
    if (__all(a > 0 && b > 0)) break;
    __builtin_amdgcn_s_sleep(1);
  }
  asm volatile("" ::: "memory");

  float c_reg = 0.0f;
  u32* hT0 = hx + (size_t)dir * (2 * HH * BB);

  #pragma unroll 1
  for (int s = 0; s < LL; ++s) {
    const int t = dir ? (LL - 1 - s) : s;

    // ---- x(s) loads from ring (guaranteed published; latency hides under poll) ----
    const u64* xb = (const u64*)(xr + ((size_t)(dir * XR + (s & 7))) * (HH * BB));
    u64 xq[2][4][4];
    #pragma unroll
    for (int tt = 0; tt < 2; ++tt) {
      const int cb = tt ? cb1 : cb0;
      #pragma unroll
      for (int s4 = 0; s4 < 4; ++s4) {
        const int bi = (cb + kko + s4 * 32) >> 1;
        #pragma unroll
        for (int i = 0; i < 4; ++i) xq[tt][s4][i] = LDA(&xb[bi + i]);
      }
    }

    // ---- producer: issue gather for x(s+XW) early, finish late ----
    const bool dop = isprod && (s + XW < LL);
    float4 pv = make_float4(0.f, 0.f, 0.f, 0.f);
    if (dop) {
      const int tp = dir ? (LL - 1 - (s + XW)) : (s + XW);
      const int tok = p.tokens[tp * BB + pb];
      if (tok >= 0) pv = *(const float4*)(p.emb + (size_t)tok * HH + pk);
    }

    // ---- per-wave wait: all 128 group blocks arrived at step s ----
    if (s) {
      for (;;) {
        int a = LDA(&slots[gb + lane * 2]);
        int b = LDA(&slots[gb + lane * 2 + 1]);
        if (__all(a >= s && b >= s)) break;
        __builtin_amdgcn_s_sleep(1);
      }
      asm volatile("" ::: "memory");  // keep h loads below the poll
    }

    // ---- h loads (first half) straight from L3, then MFMA X while in flight ----
    const u64* hb = (const u64*)(hT0 + (size_t)(s & 1) * (HH * BB));
    u64 hq[2][4][4];
    #pragma unroll
    for (int tt = 0; tt < 2; ++tt) {
      const int cb = tt ? cb1 : cb0;
      #pragma unroll
      for (int s4 = 0; s4 < 2; ++s4) {
        const int bi = (cb + kko + s4 * 32) >> 1;
        #pragma unroll
        for (int i = 0; i < 4; ++i) hq[tt][s4][i] = LDA(&hb[bi + i]);
      }
    }

    f32x4 a0 = {0.f,0.f,0.f,0.f}, a1 = {0.f,0.f,0.f,0.f};
    #pragma unroll
    for (int s4 = 0; s4 < 4; ++s4) {
      bf16x8 bh, bl;
      unpack4(xq[0][s4], bh, bl);
      MF(aXhi[s4], bh, a0); MF(aXhi[s4], bl, a0); MF(aXlo[s4], bh, a0);
      unpack4(xq[1][s4], bh, bl);
      MF(aXhi[s4], bh, a1); MF(aXhi[s4], bl, a1); MF(aXlo[s4], bh, a1);
    }

    // ---- h loads (second half) ----
    #pragma unroll
    for (int tt = 0; tt < 2; ++tt) {
      const int cb = tt ? cb1 : cb0;
      #pragma unroll
      for (int s4 = 2; s4 < 4; ++s4) {
        const int bi = (cb + kko + s4 * 32) >> 1;
        #pragma unroll
        for (int i = 0; i < 4; ++i) hq[tt][s4][i] = LDA(&hb[bi + i]);
      }
    }

    // ---- MFMA H ----
    #pragma unroll
    for (int s4 = 0; s4 < 4; ++s4) {
      bf16x8 bh, bl;
      unpack4(hq[0][s4], bh, bl);
      MF(aHhi[s4], bh, a0); MF(aHhi[s4], bl, a0); MF(aHlo[s4], bh, a0);
      unpack4(hq[1][s4], bh, bl);
      MF(aHhi[s4], bh, a1); MF(aHhi[s4], bl, a1); MF(aHlo[s4], bh, a1);
    }

    // ---- k-quarter reduce ----
    red[wv * 2 + 0][lane] = a0;
    red[wv * 2 + 1][lane] = a1;
    __syncthreads();

    if (wv < 4) {
      // wave w owns col-tile w (cols w*16+mrow); partials at slot k2*4 + w
      f32x4 sum = {0.f,0.f,0.f,0.f};
      #pragma unroll
      for (int k2 = 0; k2 < 4; ++k2) {
        f32x4 r = red[k2 * 4 + (wv >> 1) * 2 + (wv & 1)][lane];
        sum[0] += r[0]; sum[1] += r[1]; sum[2] += r[2]; sum[3] += r[3];
      }
      const int b = wv * 16 + mrow;
      float g0 = sum[0] + bias4[0];
      float g1 = sum[1] + bias4[1];
      float g2 = sum[2] + bias4[2];
      float g3 = sum[3] + bias4[3];
      float ig = sigf(g0), fg = sigf(g1), gg = tanh2(g2), og = sigf(g3);
      float m  = p.mask[t * BB + b];
      float cu = fg * c_reg + ig * gg;
      float hu = og * tanh2(cu);
      c_reg = cu * m;
      hu *= m;
      // out: plain cached store (flushed at dispatch end)
      p.out[((size_t)(t * BB + b)) * (2 * HH) + dir * HH + j0 + quad] = hu;
      // h publish: packed split-bf16 u32, relaxed agent atomic (straight to L3)
      u16 hh, ll; split1(hu, hh, ll);
      STA(hT0 + (size_t)((s & 1) ^ 1) * (HH * BB) + (b << 9) + j0 + quad,
          (u32)hh | ((u32)ll << 16));
    }

    // ---- producer finish: split + publish x(s+XW) ----
    if (dop) {
      u16 h0,h1,h2,h3,l0,l1,l2,l3;
      split1(pv.x,h0,l0); split1(pv.y,h1,l1); split1(pv.z,h2,l2); split1(pv.w,h3,l3);
      u64 w0 = ((u64)((u32)h0 | ((u32)l0 << 16))) | (((u64)((u32)h1 | ((u32)l1 << 16))) << 32);
      u64 w1 = ((u64)((u32)h2 | ((u32)l2 << 16))) | (((u64)((u32)h3 | ((u32)l3 << 16))) << 32);
      u64* dst = (u64*)(xr + ((size_t)(dir * XR + ((s + XW) & 7))) * (HH * BB))
               + (((pb << 9) + pk) >> 1);
      STA(&dst[0], w0); STA(&dst[1], w1);
    }

    // drain all publishes (h, x, out) before arriving; flag after barrier
    asm volatile("s_waitcnt vmcnt(0)" ::: "memory");
    __syncthreads();
    if (tid == 0) STA(&slots[gb + q], s + 1);
  }
}

extern "C" void kernel_launch(void* const* d_in, const int* in_sizes, int n_in,
                              void* d_out, int out_size, void* d_ws, size_t ws_size,
                              hipStream_t stream) {
  (void)in_sizes; (void)n_in; (void)out_size; (void)ws_size;
  Params prm;
  prm.tokens = (const int*)d_in[0];
  prm.mask   = (const float*)d_in[1];
  prm.emb    = (const float*)d_in[2];
  prm.WihF   = (const float*)d_in[3];
  prm.WhhF   = (const float*)d_in[4];
  prm.bihF   = (const float*)d_in[5];
  prm.bhhF   = (const float*)d_in[6];
  prm.WihB   = (const float*)d_in[7];
  prm.WhhB   = (const float*)d_in[8];
  prm.bihB   = (const float*)d_in[9];
  prm.bihB   = (const float*)d_in[9];
  prm.bhhB   = (const float*)d_in[10];
  prm.out    = (float*)d_out;
  // ws: [0, 512K)   h exchange [dir][buf][b][j] u32 (bf16 hi|lo)
  //     [512K, 2.5M) x ring    [dir][slot8][b][k] u32 (bf16 hi|lo)
  //     [2.5M, +2K)  flags: slots[256] + pslot[256]
  prm.hx  = (u32*)d_ws;
  prm.bar = (int*)((char*)d_ws + 2621440);

  hipMemsetAsync(d_ws, 0, 2625536, stream);

  void* args[] = {(void*)&prm};
  hipLaunchCooperativeKernel((const void*)lstm_mfma, dim3(NBLK), dim3(NTHR), args, 0, stream);
}

// Round 2
// 3124.695 us; speedup vs baseline: 2.7781x; 2.6846x over previous
//
#include <hip/hip_runtime.h>

// Bidirectional LSTM L=512, B=64, E=H=512 fp32 — MFMA split-bf16 persistent kernel.
// Round 5: 2-D sharding to kill the L3 all-to-all (R4 post-mortem: two different
// kernels both pinned at 16.3us/step => common bottleneck = 64MB/step of L3
// broadcast + flag-line contention, not per-block work).
//   - 2 dirs x 4 groups x 32 blocks. Group owns 16 batch cols (one MFMA N-tile,
//     no padding). Block owns 16 h-units (64 gate rows = 4 M-tiles). K split
//     8-ways across waves (K=64/wave) => B-frags have zero intra-block
//     redundancy; no LDS staging; per-block exchange read = 32KB h + 32KB x
//     (was 128KB+128KB). Total 16MB/step vs 64MB, all full-line merged.
//   - Flags: 32 per (dir,group), private cache line; ONE wave polls, others
//     park at s_barrier => ~100x less poll traffic.
//   - x B-frags for step s+1 prefetched into registers late in step s (ring
//     slack >= 2 steps); MFMA-X runs pre-poll. Only h load latency is exposed.
//   - Weights register-resident: 4mt x 2s4 x (hi,lo) x (Wih,Whh) = 128 VGPR.

#define LL 512
#define BB 64
#define HH 512
#define NBLK 256
#define NTHR 512
#define XW 4   // x pipeline depth (steps ahead)
#define XR 8   // x ring slots

typedef __attribute__((ext_vector_type(8))) __bf16 bf16x8;
typedef __attribute__((ext_vector_type(4))) float f32x4;
typedef unsigned int u32;
typedef unsigned long long u64;
typedef unsigned short u16;

struct Params {
  const int* tokens; const float* mask; const float* emb;
  const float* WihF; const float* WhhF; const float* bihF; const float* bhhF;
  const float* WihB; const float* WhhB; const float* bihB; const float* bhhB;
  float* out; u32* hx; int* bar;
};

__device__ __forceinline__ float sigf(float x)  { return 1.0f / (1.0f + __expf(-x)); }
__device__ __forceinline__ float tanh2(float x) { return 2.0f / (1.0f + __expf(-2.0f * x)) - 1.0f; }

__device__ __forceinline__ void split1(float v, u16& hi, u16& lo) {
  __bf16 h = (__bf16)v;
  __bf16 l = (__bf16)(v - (float)h);
  hi = __builtin_bit_cast(u16, h);
  lo = __builtin_bit_cast(u16, l);
}

// 4x u64 of packed (hi|lo<<16) elements -> bf16x8 hi-plane + bf16x8 lo-plane
__device__ __forceinline__ void unpack4(const u64* q, bf16x8& bh, bf16x8& bl) {
  union U { u32 w[4]; bf16x8 v; } H, L;
  #pragma unroll
  for (int i = 0; i < 4; ++i) {
    u32 lo = (u32)q[i], hi = (u32)(q[i] >> 32);
    H.w[i] = __builtin_amdgcn_perm(hi, lo, 0x05040100u);  // low16s  (bf16 hi bits)
    L.w[i] = __builtin_amdgcn_perm(hi, lo, 0x07060302u);  // high16s (bf16 lo bits)
  }
  bh = H.v; bl = L.v;
}

#define MF(A, B, C) C = __builtin_amdgcn_mfma_f32_16x16x32_bf16(A, B, C, 0, 0, 0)
#define LDA(P)    __hip_atomic_load((P), __ATOMIC_RELAXED, __HIP_MEMORY_SCOPE_AGENT)
#define STA(P, V) __hip_atomic_store((P), (V), __ATOMIC_RELAXED, __HIP_MEMORY_SCOPE_AGENT)

__launch_bounds__(NTHR, 1)
__global__ void lstm_mfma(Params p) {
  __shared__ f32x4 red[8][4][64];   // [kwave][mt][lane] partials, 32 KB

  const int tid  = threadIdx.x;
  const int blk  = blockIdx.x;
  const int dir  = blk >> 7;          // 0=fwd 1=bwd
  const int rq   = blk & 127;
  const int g    = rq >> 5;           // group 0..3: batch cols g*16..+16
  const int iq   = rq & 31;           // block-in-group: h-units iq*16..+16
  const int lane = tid & 63;
  const int wv   = tid >> 6;          // 8 waves = 8 K-slices of 64
  const int quad = lane >> 4;
  const int mrow = lane & 15;
  const int j0   = iq << 4;           // owned unit base

  const float* __restrict__ Wih = dir ? p.WihB : p.WihF;
  const float* __restrict__ Whh = dir ? p.WhhB : p.WhhF;
  const float* bih = dir ? p.bihB : p.bihF;
  const float* bhh = dir ? p.bhhB : p.bhhF;

  // ---- one-time: weights -> register A-fragments, split bf16 hi/lo ----
  // A row m of tile mt -> W row (m&3)*HH + j0 + mt*4 + (m>>2)
  // => C lane regs 0..3 = 4 gates of unit (j0 + mt*4 + quad), col mrow.
  bf16x8 aXhi[4][2], aXlo[4][2], aHhi[4][2], aHlo[4][2];
  #pragma unroll
  for (int mt = 0; mt < 4; ++mt) {
    const int grow = (mrow & 3) * HH + j0 + mt * 4 + (mrow >> 2);
    #pragma unroll
    for (int s4 = 0; s4 < 2; ++s4) {
      const int kb = wv * 64 + s4 * 32 + quad * 8;
      const float* wp = Wih + (size_t)grow * HH + kb;
      const float* wq = Whh + (size_t)grow * HH + kb;
      #pragma unroll
      for (int j = 0; j < 8; ++j) {
        float v = wp[j];
        __bf16 h = (__bf16)v;
        aXhi[mt][s4][j] = h; aXlo[mt][s4][j] = (__bf16)(v - (float)h);
        float u = wq[j];
        __bf16 hb2 = (__bf16)u;
        aHhi[mt][s4][j] = hb2; aHlo[mt][s4][j] = (__bf16)(u - (float)hb2);
      }
    }
  }
  float bias4[4];
  {
    const int ju = j0 + (wv & 3) * 4 + quad;   // valid where used (wv<4)
    #pragma unroll
    for (int g4 = 0; g4 < 4; ++g4)
      bias4[g4] = bih[g4 * HH + ju] + bhh[g4 * HH + ju];
  }

  // ---- exchange buffers ----
  u32* hx    = p.hx;                                   // [dir][buf][g][b16][j512]
  u32* xr    = p.hx + 2 * 2 * 4 * 16 * 512;            // [dir][slot][g][b16][k512]
  int* slots = p.bar + (dir * 4 + g) * 64;             // 32 used, line-padded
  int* pslot = p.bar + 2048 + (dir * 4 + g) * 64;

  // x producer: wave 7. Block covers local col iq>>1, k-half iq&1 (256 k).
  const bool isprod = (wv == 7);
  const int pb = iq >> 1;                       // local batch col 0..15
  const int pk = ((iq & 1) << 8) + (lane << 2); // 4 floats per lane

  // ---- prologue: publish x(0..XW-1), group handshake ----
  if (isprod) {
    #pragma unroll
    for (int w = 0; w < XW; ++w) {
      const int tp = dir ? (LL - 1 - w) : w;
      const int tok = p.tokens[tp * BB + g * 16 + pb];
      float4 v = make_float4(0.f, 0.f, 0.f, 0.f);
      if (tok >= 0) v = *(const float4*)(p.emb + (size_t)tok * HH + pk);
      u16 h0,h1,h2,h3,l0,l1,l2,l3;
      split1(v.x,h0,l0); split1(v.y,h1,l1); split1(v.z,h2,l2); split1(v.w,h3,l3);
      u64 w0 = ((u64)((u32)h0 | ((u32)l0 << 16))) | (((u64)((u32)h1 | ((u32)l1 << 16))) << 32);
      u64 w1 = ((u64)((u32)h2 | ((u32)l2 << 16))) | (((u64)((u32)h3 | ((u32)l3 << 16))) << 32);
      u64* dst = (u64*)(xr + ((size_t)((dir * XR + w) * 4 + g)) * 8192 + pb * 512 + pk);
      STA(&dst[0], w0); STA(&dst[1], w1);
    }
  }
  asm volatile("s_waitcnt vmcnt(0)" ::: "memory");
  __syncthreads();
  if (tid == 0) STA(&pslot[iq], 1);
  if (wv == 0) {
    for (;;) {
      int v = (lane < 32) ? LDA(&pslot[lane]) : 1;
      if (__all(v > 0)) break;
      __builtin_amdgcn_s_sleep(1);
    }
    asm volatile("" ::: "memory");
  }
  __syncthreads();

  // ---- x(0) B-frags into registers ----
  u64 xq[2][4];
  {
    const u32* xb = xr + ((size_t)((dir * XR + 0) * 4 + g)) * 8192;
    #pragma unroll
    for (int s4 = 0; s4 < 2; ++s4) {
      const u64* qp = (const u64*)(xb + mrow * 512 + wv * 64 + s4 * 32 + quad * 8);
      #pragma unroll
      for (int i = 0; i < 4; ++i) xq[s4][i] = LDA(&qp[i]);
    }
  }

  float c_reg = 0.0f;

  #pragma unroll 1
  for (int s = 0; s < LL; ++s) {
    const int t = dir ? (LL - 1 - s) : s;

    // ---- producer: issue gather for x(s+XW) early, finish late ----
    const bool dop = isprod && (s + XW < LL);
    float4 pv = make_float4(0.f, 0.f, 0.f, 0.f);
    if (dop) {
      const int tp = dir ? (LL - 1 - (s + XW)) : (s + XW);
      const int tok = p.tokens[tp * BB + g * 16 + pb];
      if (tok >= 0) pv = *(const float4*)(p.emb + (size_t)tok * HH + pk);
    }

    // ---- MFMA X from registers (pre-poll; xq loaded last step) ----
    f32x4 acc[4];
    #pragma unroll
    for (int mt = 0; mt < 4; ++mt) acc[mt] = (f32x4){0.f,0.f,0.f,0.f};
    #pragma unroll
    for (int s4 = 0; s4 < 2; ++s4) {
      bf16x8 bh, bl;
      unpack4(xq[s4], bh, bl);
      #pragma unroll
      for (int mt = 0; mt < 4; ++mt) {
        MF(aXhi[mt][s4], bh, acc[mt]);
        MF(aXhi[mt][s4], bl, acc[mt]);
        MF(aXlo[mt][s4], bh, acc[mt]);
      }
    }

    // ---- wait: all 32 group blocks arrived at step s (wave0 polls) ----
    if (s) {
      if (wv == 0) {
        for (;;) {
          int v = (lane < 32) ? LDA(&slots[lane]) : s;
          if (__all(v >= s)) break;
          __builtin_amdgcn_s_sleep(1);
        }
        asm volatile("" ::: "memory");  // keep h loads below the poll
      }
      __syncthreads();
    }

    // ---- h(s-1) B-frags straight from L3 (32 KB/block, line-merged) ----
    const u32* hb = hx + ((size_t)((dir * 2 + (s & 1)) * 4 + g)) * 8192;
    u64 hq[2][4];
    #pragma unroll
    for (int s4 = 0; s4 < 2; ++s4) {
      const u64* qp = (const u64*)(hb + mrow * 512 + wv * 64 + s4 * 32 + quad * 8);
      #pragma unroll
      for (int i = 0; i < 4; ++i) hq[s4][i] = LDA(&qp[i]);
    }

    // ---- MFMA H ----
    #pragma unroll
    for (int s4 = 0; s4 < 2; ++s4) {
      bf16x8 bh, bl;
      unpack4(hq[s4], bh, bl);
      #pragma unroll
      for (int mt = 0; mt < 4; ++mt) {
        MF(aHhi[mt][s4], bh, acc[mt]);
        MF(aHhi[mt][s4], bl, acc[mt]);
        MF(aHlo[mt][s4], bh, acc[mt]);
      }
    }

    // ---- prefetch x(s+1) B-frags (ring slack >= 2 steps guarantees data) ----
    if (s + 1 < LL) {
      const u32* xb = xr + ((size_t)((dir * XR + ((s + 1) & 7)) * 4 + g)) * 8192;
      #pragma unroll
      for (int s4 = 0; s4 < 2; ++s4) {
        const u64* qp = (const u64*)(xb + mrow * 512 + wv * 64 + s4 * 32 + quad * 8);
        #pragma unroll
        for (int i = 0; i < 4; ++i) xq[s4][i] = LDA(&qp[i]);
      }
    }

    // ---- K-reduce across 8 waves ----
    #pragma unroll
    for (int mt = 0; mt < 4; ++mt) red[wv][mt][lane] = acc[mt];
    __syncthreads();

    if (wv < 4) {   // wave mt owns M-tile mt
      f32x4 sum = {0.f,0.f,0.f,0.f};
      #pragma unroll
      for (int kv = 0; kv < 8; ++kv) {
        f32x4 r = red[kv][wv][lane];
        sum[0] += r[0]; sum[1] += r[1]; sum[2] += r[2]; sum[3] += r[3];
      }
      const int b = g * 16 + mrow;
      float g0 = sum[0] + bias4[0];
      float g1 = sum[1] + bias4[1];
      float g2 = sum[2] + bias4[2];
      float g3 = sum[3] + bias4[3];
      float ig = sigf(g0), fg = sigf(g1), gg = tanh2(g2), og = sigf(g3);
      float m  = p.mask[t * BB + b];
      float cu = fg * c_reg + ig * gg;
      float hu = og * tanh2(cu);
      c_reg = cu * m;
      hu *= m;
      const int ju = j0 + wv * 4 + quad;
      // out: plain cached store (flushed at dispatch end)
      p.out[((size_t)(t * BB + b)) * (2 * HH) + dir * HH + ju] = hu;
      // h publish: packed split-bf16 u32, relaxed agent atomic (straight to L3)
      u16 hh, ll; split1(hu, hh, ll);
      STA(hx + ((size_t)((dir * 2 + ((s & 1) ^ 1)) * 4 + g)) * 8192 + mrow * 512 + ju,
          (u32)hh | ((u32)ll << 16));
    }

    // ---- producer finish: split + publish x(s+XW) ----
    if (dop) {
      u16 h0,h1,h2,h3,l0,l1,l2,l3;
      split1(pv.x,h0,l0); split1(pv.y,h1,l1); split1(pv.z,h2,l2); split1(pv.w,h3,l3);
      u64 w0 = ((u64)((u32)h0 | ((u32)l0 << 16))) | (((u64)((u32)h1 | ((u32)l1 << 16))) << 32);
      u64 w1 = ((u64)((u32)h2 | ((u32)l2 << 16))) | (((u64)((u32)h3 | ((u32)l3 << 16))) << 32);
      u64* dst = (u64*)(xr + ((size_t)((dir * XR + ((s + XW) & 7)) * 4 + g)) * 8192
                        + pb * 512 + pk);
      STA(&dst[0], w0); STA(&dst[1], w1);
    }

    // drain publishes (h, x, out) + prefetch loads; then arrive
    asm volatile("s_waitcnt vmcnt(0)" ::: "memory");
    __syncthreads();
    if (tid == 0) STA(&slots[iq], s + 1);
  }
}

extern "C" void kernel_launch(void* const* d_in, const int* in_sizes, int n_in,
                              void* d_out, int out_size, void* d_ws, size_t ws_size,
                              hipStream_t stream) {
  (void)in_sizes; (void)n_in; (void)out_size; (void)ws_size;
  Params prm;
  prm.tokens = (const int*)d_in[0];
  prm.mask   = (const float*)d_in[1];
  prm.emb    = (const float*)d_in[2];
  prm.WihF   = (const float*)d_in[3];
  prm.WhhF   = (const float*)d_in[4];
  prm.bihF   = (const float*)d_in[5];
  prm.bhhF   = (const float*)d_in[6];
  prm.WihB   = (const float*)d_in[7];
  prm.WhhB   = (const float*)d_in[8];
  prm.bihB   = (const float*)d_in[9];
  prm.bhhB   = (const float*)d_in[10];
  prm.out    = (float*)d_out;
  // ws: [0, 512K)      h exchange [dir][buf][g][b16][j512] u32 (bf16 hi|lo)
  //     [512K, 2.5M)   x ring    [dir][slot8][g][b16][k512] u32
  //     [2.5M, +16K)   flags: slots (2048 ints, line-padded) + pslot (2048)
  prm.hx  = (u32*)d_ws;
  prm.bar = (int*)((char*)d_ws + 2621440);

  hipMemsetAsync(d_ws, 0, 2637824, stream);

  void* args[] = {(void*)&prm};
  hipLaunchCooperativeKernel((const void*)lstm_mfma, dim3(NBLK), dim3(NTHR), args, 0, stream);
}

// Round 3
// 3056.088 us; speedup vs baseline: 2.8405x; 1.0224x over previous
//
#include <hip/hip_runtime.h>

// Bidirectional LSTM L=512, B=64, E=H=512 fp32 — MFMA split-bf16 persistent kernel.
// Round 6: latency-chain attack (R5 post-mortem: 5.9us/step with all util <12%,
// FETCH 2.2MB/step vs 16MB logical => L2 absorbs reads; pure handshake latency).
//   (1) XCD-colocation: gang = blk&7, iq = blk>>3. Round-robin dispatch puts each
//       32-block gang on ONE XCD's 32 CUs => h/x/flag coherence hops XCD-local.
//       (Perf heuristic only — agent-scope atomics keep it correct regardless.)
//   (2) Per-wave poll: wave wv needs h-units [wv*64,+64) = blocks 4wv..4wv+3 only.
//       Each wave polls its own 4 flags, then loads h + MFMA-H immediately. No
//       single-poller wave + no block-wide release barrier. Global step coupling
//       preserved: flag(s+1) follows all waves via the reduce barrier.
//   (3) x(s+1) prefetch moved AFTER the flag store: the pre-flag vmcnt(0) now
//       drains only stores (h/out/x-pub), not 8 L3 loads; prefetch latency hides
//       under the next step's poll. (Slack proof: flag(s)>=s observed by all =>
//       x(s+1) was published before producers' flag(s-2), s>=s-2; s<=3 covered
//       by the XW=4 prologue.)

#define LL 512
#define BB 64
#define HH 512
#define NBLK 256
#define NTHR 512
#define XW 4   // x pipeline depth (steps ahead)
#define XR 8   // x ring slots

typedef __attribute__((ext_vector_type(8))) __bf16 bf16x8;
typedef __attribute__((ext_vector_type(4))) float f32x4;
typedef unsigned int u32;
typedef unsigned long long u64;
typedef unsigned short u16;

struct Params {
  const int* tokens; const float* mask; const float* emb;
  const float* WihF; const float* WhhF; const float* bihF; const float* bhhF;
  const float* WihB; const float* WhhB; const float* bihB; const float* bhhB;
  float* out; u32* hx; int* bar;
};

__device__ __forceinline__ float sigf(float x)  { return 1.0f / (1.0f + __expf(-x)); }
__device__ __forceinline__ float tanh2(float x) { return 2.0f / (1.0f + __expf(-2.0f * x)) - 1.0f; }

__device__ __forceinline__ void split1(float v, u16& hi, u16& lo) {
  __bf16 h = (__bf16)v;
  __bf16 l = (__bf16)(v - (float)h);
  hi = __builtin_bit_cast(u16, h);
  lo = __builtin_bit_cast(u16, l);
}

// 4x u64 of packed (hi|lo<<16) elements -> bf16x8 hi-plane + bf16x8 lo-plane
__device__ __forceinline__ void unpack4(const u64* q, bf16x8& bh, bf16x8& bl) {
  union U { u32 w[4]; bf16x8 v; } H, L;
  #pragma unroll
  for (int i = 0; i < 4; ++i) {
    u32 lo = (u32)q[i], hi = (u32)(q[i] >> 32);
    H.w[i] = __builtin_amdgcn_perm(hi, lo, 0x05040100u);  // low16s  (bf16 hi bits)
    L.w[i] = __builtin_amdgcn_perm(hi, lo, 0x07060302u);  // high16s (bf16 lo bits)
  }
  bh = H.v; bl = L.v;
}

#define MF(A, B, C) C = __builtin_amdgcn_mfma_f32_16x16x32_bf16(A, B, C, 0, 0, 0)
#define LDA(P)    __hip_atomic_load((P), __ATOMIC_RELAXED, __HIP_MEMORY_SCOPE_AGENT)
#define STA(P, V) __hip_atomic_store((P), (V), __ATOMIC_RELAXED, __HIP_MEMORY_SCOPE_AGENT)

__launch_bounds__(NTHR, 1)
__global__ void lstm_mfma(Params p) {
  __shared__ f32x4 red[8][4][64];   // [kwave][mt][lane] partials, 32 KB

  const int tid  = threadIdx.x;
  const int blk  = blockIdx.x;
  const int gang = blk & 7;           // XCD-colocated gang (round-robin dispatch)
  const int dir  = gang >> 2;         // 0=fwd 1=bwd
  const int g    = gang & 3;          // group: batch cols g*16..+16
  const int iq   = blk >> 3;          // block-in-gang: h-units iq*16..+16
  const int lane = tid & 63;
  const int wv   = tid >> 6;          // 8 waves = 8 K-slices of 64
  const int quad = lane >> 4;
  const int mrow = lane & 15;
  const int j0   = iq << 4;           // owned unit base

  const float* __restrict__ Wih = dir ? p.WihB : p.WihF;
  const float* __restrict__ Whh = dir ? p.WhhB : p.WhhF;
  const float* bih = dir ? p.bihB : p.bihF;
  const float* bhh = dir ? p.bhhB : p.bhhF;

  // ---- one-time: weights -> register A-fragments, split bf16 hi/lo ----
  // A row m of tile mt -> W row (m&3)*HH + j0 + mt*4 + (m>>2)
  // => C lane regs 0..3 = 4 gates of unit (j0 + mt*4 + quad), col mrow.
  bf16x8 aXhi[4][2], aXlo[4][2], aHhi[4][2], aHlo[4][2];
  #pragma unroll
  for (int mt = 0; mt < 4; ++mt) {
    const int grow = (mrow & 3) * HH + j0 + mt * 4 + (mrow >> 2);
    #pragma unroll
    for (int s4 = 0; s4 < 2; ++s4) {
      const int kb = wv * 64 + s4 * 32 + quad * 8;
      const float* wp = Wih + (size_t)grow * HH + kb;
      const float* wq = Whh + (size_t)grow * HH + kb;
      #pragma unroll
      for (int j = 0; j < 8; ++j) {
        float v = wp[j];
        __bf16 h = (__bf16)v;
        aXhi[mt][s4][j] = h; aXlo[mt][s4][j] = (__bf16)(v - (float)h);
        float u = wq[j];
        __bf16 hb2 = (__bf16)u;
        aHhi[mt][s4][j] = hb2; aHlo[mt][s4][j] = (__bf16)(u - (float)hb2);
      }
    }
  }
  float bias4[4];
  {
    const int ju = j0 + (wv & 3) * 4 + quad;   // valid where used (wv<4)
    #pragma unroll
    for (int g4 = 0; g4 < 4; ++g4)
      bias4[g4] = bih[g4 * HH + ju] + bhh[g4 * HH + ju];
  }

  // ---- exchange buffers ----
  u32* hx    = p.hx;                                   // [dir][buf][g][b16][j512]
  u32* xr    = p.hx + 2 * 2 * 4 * 16 * 512;            // [dir][slot][g][b16][k512]
  int* slots = p.bar + gang * 64;                      // 32 used, line-padded
  int* pslot = p.bar + 2048 + gang * 64;

  // x producer: wave 7. Block covers local col iq>>1, k-half iq&1 (256 k).
  const bool isprod = (wv == 7);
  const int pb = iq >> 1;                       // local batch col 0..15
  const int pk = ((iq & 1) << 8) + (lane << 2); // 4 floats per lane

  // ---- prologue: publish x(0..XW-1), gang handshake ----
  if (isprod) {
    #pragma unroll
    for (int w = 0; w < XW; ++w) {
      const int tp = dir ? (LL - 1 - w) : w;
      const int tok = p.tokens[tp * BB + g * 16 + pb];
      float4 v = make_float4(0.f, 0.f, 0.f, 0.f);
      if (tok >= 0) v = *(const float4*)(p.emb + (size_t)tok * HH + pk);
      u16 h0,h1,h2,h3,l0,l1,l2,l3;
      split1(v.x,h0,l0); split1(v.y,h1,l1); split1(v.z,h2,l2); split1(v.w,h3,l3);
      u64 w0 = ((u64)((u32)h0 | ((u32)l0 << 16))) | (((u64)((u32)h1 | ((u32)l1 << 16))) << 32);
      u64 w1 = ((u64)((u32)h2 | ((u32)l2 << 16))) | (((u64)((u32)h3 | ((u32)l3 << 16))) << 32);
      u64* dst = (u64*)(xr + ((size_t)((dir * XR + w) * 4 + g)) * 8192 + pb * 512 + pk);
      STA(&dst[0], w0); STA(&dst[1], w1);
    }
  }
  asm volatile("s_waitcnt vmcnt(0)" ::: "memory");
  __syncthreads();
  if (tid == 0) STA(&pslot[iq], 1);
  if (wv == 0) {
    for (;;) {
      int v = (lane < 32) ? LDA(&pslot[lane]) : 1;
      if (__all(v > 0)) break;
      __builtin_amdgcn_s_sleep(1);
    }
    asm volatile("" ::: "memory");
  }
  __syncthreads();

  // ---- x(0) B-frags into registers ----
  u64 xq[2][4];
  {
    const u32* xb = xr + ((size_t)((dir * XR + 0) * 4 + g)) * 8192;
    #pragma unroll
    for (int s4 = 0; s4 < 2; ++s4) {
      const u64* qp = (const u64*)(xb + mrow * 512 + wv * 64 + s4 * 32 + quad * 8);
      #pragma unroll
      for (int i = 0; i < 4; ++i) xq[s4][i] = LDA(&qp[i]);
    }
  }

  float c_reg = 0.0f;

  #pragma unroll 1
  for (int s = 0; s < LL; ++s) {
    const int t = dir ? (LL - 1 - s) : s;

    // ---- producer: issue gather for x(s+XW) early, finish late ----
    const bool dop = isprod && (s + XW < LL);
    float4 pv = make_float4(0.f, 0.f, 0.f, 0.f);
    if (dop) {
      const int tp = dir ? (LL - 1 - (s + XW)) : (s + XW);
      const int tok = p.tokens[tp * BB + g * 16 + pb];
      if (tok >= 0) pv = *(const float4*)(p.emb + (size_t)tok * HH + pk);
    }

    // ---- MFMA X from registers (pre-poll; xq prefetched last step) ----
    f32x4 acc[4];
    #pragma unroll
    for (int mt = 0; mt < 4; ++mt) acc[mt] = (f32x4){0.f,0.f,0.f,0.f};
    #pragma unroll
    for (int s4 = 0; s4 < 2; ++s4) {
      bf16x8 bh, bl;
      unpack4(xq[s4], bh, bl);
      #pragma unroll
      for (int mt = 0; mt < 4; ++mt) {
        MF(aXhi[mt][s4], bh, acc[mt]);
        MF(aXhi[mt][s4], bl, acc[mt]);
        MF(aXlo[mt][s4], bh, acc[mt]);
      }
    }

    // ---- per-wave poll: wave wv's k-slice comes from blocks 4wv..4wv+3 ----
    if (s) {
      for (;;) {
        int v = (lane < 4) ? LDA(&slots[wv * 4 + lane]) : s;
        if (__all(v >= s)) break;
        __builtin_amdgcn_s_sleep(1);
      }
      asm volatile("" ::: "memory");  // keep h loads below the poll
    }

    // ---- h(s-1) B-frags straight from coherence point (per-wave, post-poll) ----
    const u32* hb = hx + ((size_t)((dir * 2 + (s & 1)) * 4 + g)) * 8192;
    u64 hq[2][4];
    #pragma unroll
    for (int s4 = 0; s4 < 2; ++s4) {
      const u64* qp = (const u64*)(hb + mrow * 512 + wv * 64 + s4 * 32 + quad * 8);
      #pragma unroll
      for (int i = 0; i < 4; ++i) hq[s4][i] = LDA(&qp[i]);
    }

    // ---- MFMA H ----
    #pragma unroll
    for (int s4 = 0; s4 < 2; ++s4) {
      bf16x8 bh, bl;
      unpack4(hq[s4], bh, bl);
      #pragma unroll
      for (int mt = 0; mt < 4; ++mt) {
        MF(aHhi[mt][s4], bh, acc[mt]);
        MF(aHhi[mt][s4], bl, acc[mt]);
        MF(aHlo[mt][s4], bh, acc[mt]);
      }
    }

    // ---- K-reduce across 8 waves ----
    #pragma unroll
    for (int mt = 0; mt < 4; ++mt) red[wv][mt][lane] = acc[mt];
    __syncthreads();

    if (wv < 4) {   // wave mt owns M-tile mt
      f32x4 sum = {0.f,0.f,0.f,0.f};
      #pragma unroll
      for (int kv = 0; kv < 8; ++kv) {
        f32x4 r = red[kv][wv][lane];
        sum[0] += r[0]; sum[1] += r[1]; sum[2] += r[2]; sum[3] += r[3];
      }
      const int b = g * 16 + mrow;
      float g0 = sum[0] + bias4[0];
      float g1 = sum[1] + bias4[1];
      float g2 = sum[2] + bias4[2];
      float g3 = sum[3] + bias4[3];
      float ig = sigf(g0), fg = sigf(g1), gg = tanh2(g2), og = sigf(g3);
      float m  = p.mask[t * BB + b];
      float cu = fg * c_reg + ig * gg;
      float hu = og * tanh2(cu);
      c_reg = cu * m;
      hu *= m;
      const int ju = j0 + wv * 4 + quad;
      // out: plain cached store (flushed at dispatch end)
      p.out[((size_t)(t * BB + b)) * (2 * HH) + dir * HH + ju] = hu;
      // h publish: packed split-bf16 u32, relaxed agent atomic
      u16 hh, ll; split1(hu, hh, ll);
      STA(hx + ((size_t)((dir * 2 + ((s & 1) ^ 1)) * 4 + g)) * 8192 + mrow * 512 + ju,
          (u32)hh | ((u32)ll << 16));
    }

    // ---- producer finish: split + publish x(s+XW) ----
    if (dop) {
      u16 h0,h1,h2,h3,l0,l1,l2,l3;
      split1(pv.x,h0,l0); split1(pv.y,h1,l1); split1(pv.z,h2,l2); split1(pv.w,h3,l3);
      u64 w0 = ((u64)((u32)h0 | ((u32)l0 << 16))) | (((u64)((u32)h1 | ((u32)l1 << 16))) << 32);
      u64 w1 = ((u64)((u32)h2 | ((u32)l2 << 16))) | (((u64)((u32)h3 | ((u32)l3 << 16))) << 32);
      u64* dst = (u64*)(xr + ((size_t)((dir * XR + ((s + XW) & 7)) * 4 + g)) * 8192
                        + pb * 512 + pk);
      STA(&dst[0], w0); STA(&dst[1], w1);
    }

    // ---- drain STORES only (x prefetch not yet issued); arrive; flag ----
    asm volatile("s_waitcnt vmcnt(0)" ::: "memory");
    __syncthreads();
    if (tid == 0) STA(&slots[iq], s + 1);

    // ---- x(s+1) prefetch AFTER flag: latency hides under next step's poll ----
    if (s + 1 < LL) {
      const u32* xb = xr + ((size_t)((dir * XR + ((s + 1) & 7)) * 4 + g)) * 8192;
      #pragma unroll
      for (int s4 = 0; s4 < 2; ++s4) {
        const u64* qp = (const u64*)(xb + mrow * 512 + wv * 64 + s4 * 32 + quad * 8);
        #pragma unroll
        for (int i = 0; i < 4; ++i) xq[s4][i] = LDA(&qp[i]);
      }
    }
  }
}

extern "C" void kernel_launch(void* const* d_in, const int* in_sizes, int n_in,
                              void* d_out, int out_size, void* d_ws, size_t ws_size,
                              hipStream_t stream) {
  (void)in_sizes; (void)n_in; (void)out_size; (void)ws_size;
  Params prm;
  prm.tokens = (const int*)d_in[0];
  prm.mask   = (const float*)d_in[1];
  prm.emb    = (const float*)d_in[2];
  prm.WihF   = (const float*)d_in[3];
  prm.WhhF   = (const float*)d_in[4];
  prm.bihF   = (const float*)d_in[5];
  prm.bhhF   = (const float*)d_in[6];
  prm.WihB   = (const float*)d_in[7];
  prm.WhhB   = (const float*)d_in[8];
  prm.bihB   = (const float*)d_in[9];
  prm.bhhB   = (const float*)d_in[10];
  prm.out    = (float*)d_out;
  // ws: [0, 512K)      h exchange [dir][buf][g][b16][j512] u32 (bf16 hi|lo)
  //     [512K, 2.5M)   x ring    [dir][slot8][g][b16][k512] u32
  //     [2.5M, +16K)   flags: slots (2048 ints, line-padded) + pslot (2048)
  prm.hx  = (u32*)d_ws;
  prm.bar = (int*)((char*)d_ws + 2621440);

  hipMemsetAsync(d_ws, 0, 2637824, stream);

  void* args[] = {(void*)&prm};
  hipLaunchCooperativeKernel((const void*)lstm_mfma, dim3(NBLK), dim3(NTHR), args, 0, stream);
}